// Round 15
// baseline (451.789 us; speedup 1.0000x reference)
//
#include <hip/hip_runtime.h>
#include <cstdint>

#define D 128
#define LNUM 3

typedef short short8 __attribute__((ext_vector_type(8)));
typedef float f32x4 __attribute__((ext_vector_type(4)));
typedef float f32x2 __attribute__((ext_vector_type(2)));
typedef uint32_t u32x4 __attribute__((ext_vector_type(4)));

static __device__ __forceinline__ float wred_sum(float x) {
#pragma unroll
    for (int off = 32; off; off >>= 1) x += __shfl_xor(x, off);
    return x;
}
static __device__ __forceinline__ float wred_max(float x) {
#pragma unroll
    for (int off = 32; off; off >>= 1) x = fmaxf(x, __shfl_xor(x, off));
    return x;
}
static __device__ __forceinline__ uint32_t f2bf_rne(float x) {
    uint32_t u = __float_as_uint(x);
    uint32_t r = u + 0x7fffu + ((u >> 16) & 1u);
    return r >> 16;
}

// ---------------- pre: Wt transpose->bf16, vbuf = We@ae, hist ----------------

__global__ __launch_bounds__(256) void pre_k(const float* __restrict__ W, const float* __restrict__ We,
                                             const float* __restrict__ ae,
                                             const int* __restrict__ dst,
                                             uint16_t* __restrict__ Wt, float* __restrict__ vbuf,
                                             int* __restrict__ cnt, int E) {
    int tid = blockIdx.x * 256 + threadIdx.x;
    int stride = gridDim.x * 256;
    for (int e = tid; e < E; e += stride) atomicAdd(&cnt[dst[e]], 1);
    for (int i = tid; i < LNUM * D * D; i += stride) {
        int l = i >> 14;
        int r = i & (D * D - 1);
        int j = r >> 7, k = r & 127;
        Wt[i] = (uint16_t)f2bf_rne(W[(size_t)l * D * D + (size_t)k * D + j]);
    }
    if (tid < LNUM * D) {
        int l = tid >> 7, j = tid & 127;
        const float* Wrow = We + ((size_t)l * D + j) * D;
        const float* a = ae + (size_t)l * D;
        float s = 0.f;
        for (int d = 0; d < D; ++d) s += Wrow[d] * a[d];
        vbuf[tid] = s;
    }
}

// ---------------- exclusive scan of cnt -> rowptr ----------------

__global__ __launch_bounds__(1024) void scan_k(const int* __restrict__ cnt, int* __restrict__ rowptr, int N) {
    __shared__ int sh[1024];
    int t = threadIdx.x;
    int chunk = (N + 1023) >> 10;
    int b = t * chunk;
    int e = min(b + chunk, N);
    int s = 0;
    for (int i = b; i < e; ++i) s += cnt[i];
    sh[t] = s;
    __syncthreads();
    for (int off = 1; off < 1024; off <<= 1) {
        int v = (t >= off) ? sh[t - off] : 0;
        __syncthreads();
        sh[t] += v;
        __syncthreads();
    }
    int run = sh[t] - s;  // exclusive
    for (int i = b; i < e; ++i) { rowptr[i] = run; run += cnt[i]; }
    if (t == 1023) rowptr[N] = sh[1023];
}

// ---------------- gemm body; A either bf16 (Ab) or f32 (Af); NT stores to hbf ----------------

static __device__ __forceinline__ void gemm_body(uint4* As, int bid, int t,
                                                 const uint16_t* __restrict__ Ab,
                                                 const float* __restrict__ Af,
                                                 const uint16_t* __restrict__ Wt,
                                                 const float* __restrict__ as_,
                                                 const float* __restrict__ ad_,
                                                 uint16_t* __restrict__ hbf,
                                                 float* __restrict__ hs, float* __restrict__ hd, int N) {
    int row0 = bid * 64;
    if (Af) {
#pragma unroll
        for (int it = 0; it < 4; ++it) {
            int idx2 = it * 256 + t;
            int r = idx2 >> 4, s = idx2 & 15;
            int gr = row0 + r;
            uint4 o = make_uint4(0u, 0u, 0u, 0u);
            if (gr < N) {
                float4 v0 = *(const float4*)&Af[(size_t)gr * D + s * 8];
                float4 v1 = *(const float4*)&Af[(size_t)gr * D + s * 8 + 4];
                o.x = f2bf_rne(v0.x) | (f2bf_rne(v0.y) << 16);
                o.y = f2bf_rne(v0.z) | (f2bf_rne(v0.w) << 16);
                o.z = f2bf_rne(v1.x) | (f2bf_rne(v1.y) << 16);
                o.w = f2bf_rne(v1.z) | (f2bf_rne(v1.w) << 16);
            }
            As[r * 16 + (s ^ (r & 7))] = o;
        }
    } else {
#pragma unroll
        for (int it = 0; it < 4; ++it) {
            int idx2 = it * 256 + t;
            int r = idx2 >> 4, s = idx2 & 15;
            int gr = row0 + r;
            uint4 v = make_uint4(0u, 0u, 0u, 0u);
            if (gr < N) v = *(const uint4*)&Ab[(size_t)gr * D + s * 8];
            As[r * 16 + (s ^ (r & 7))] = v;
        }
    }
    __syncthreads();
    int w = t >> 6, l = t & 63;
    int lrow = l & 15, lk = l >> 4;
    int rbase = w * 16;
    short8 afrag[4];
#pragma unroll
    for (int ks = 0; ks < 4; ++ks) {
        int r = rbase + lrow;
        int s = (ks * 4 + lk) ^ (r & 7);
        afrag[ks] = __builtin_bit_cast(short8, As[r * 16 + s]);
    }
    float psum[4] = {0.f, 0.f, 0.f, 0.f}, pdum[4] = {0.f, 0.f, 0.f, 0.f};
#pragma unroll
    for (int ct = 0; ct < 8; ++ct) {
        f32x4 acc = {0.f, 0.f, 0.f, 0.f};
#pragma unroll
        for (int ks = 0; ks < 4; ++ks) {
            short8 b = *(const short8*)&Wt[(size_t)(ct * 16 + lrow) * D + ks * 32 + lk * 8];
            acc = __builtin_amdgcn_mfma_f32_16x16x32_bf16(afrag[ks], b, acc, 0, 0, 0);
        }
        int col_g = ct * 16 + lrow;
        float av = as_[col_g], dv = ad_[col_g];
#pragma unroll
        for (int r = 0; r < 4; ++r) {
            float v = acc[r];
            psum[r] += v * av;
            pdum[r] += v * dv;
            int row_g = row0 + rbase + lk * 4 + r;
            if (row_g < N)
                __builtin_nontemporal_store((uint16_t)f2bf_rne(v), &hbf[(size_t)row_g * D + col_g]);
        }
    }
#pragma unroll
    for (int r = 0; r < 4; ++r) {
        float ps = psum[r], pd = pdum[r];
#pragma unroll
        for (int off = 1; off < 16; off <<= 1) {
            ps += __shfl_xor(ps, off);
            pd += __shfl_xor(pd, off);
        }
        if (lrow == 0) {
            int row_g = row0 + rbase + lk * 4 + r;
            if (row_g < N) { hs[row_g] = ps; hd[row_g] = pd; }
        }
    }
}

// ---------------- merged: gemm0 (f32 A, blocks < NB_G) + fillec (rest; NT ea loads) ----------------

__global__ __launch_bounds__(256) void fg_k(const float* __restrict__ x, const uint16_t* __restrict__ Wt,
                                            const float* __restrict__ as_, const float* __restrict__ ad_,
                                            uint16_t* __restrict__ hbf, float* __restrict__ hs,
                                            float* __restrict__ hd, int N,
                                            const float* __restrict__ ea, const float* __restrict__ vbuf,
                                            const int* __restrict__ src, const int* __restrict__ dst,
                                            const int* __restrict__ rowptr, int* __restrict__ cnt,
                                            uint32_t* __restrict__ rec, int E, int NB_G) {
    __shared__ uint4 As[64 * 16];
    int t = threadIdx.x;
    if ((int)blockIdx.x < NB_G) {
        gemm_body(As, blockIdx.x, t, nullptr, x, Wt, as_, ad_, hbf, hs, hd, N);
        return;
    }
    int bid = blockIdx.x - NB_G;
    int nbF = gridDim.x - NB_G;
    int sub = t & 7;
    float4 vr[3][4];
#pragma unroll
    for (int l = 0; l < 3; ++l)
#pragma unroll
        for (int i = 0; i < 4; ++i)
            vr[l][i] = *(const float4*)&vbuf[l * D + sub * 16 + i * 4];

    for (int e0 = bid * 32; e0 < E; e0 += nbF * 32) {
        int e = e0 + (t >> 3);
        if (e >= E) continue;
        const f32x4* row = (const f32x4*)(ea + (size_t)e * D + sub * 16);
        float p0 = 0.f, p1 = 0.f, p2 = 0.f;
#pragma unroll
        for (int i = 0; i < 4; ++i) {
            f32x4 v = __builtin_nontemporal_load(&row[i]);   // 410MB stream read once: keep L2 clean
            p0 += v.x * vr[0][i].x + v.y * vr[0][i].y + v.z * vr[0][i].z + v.w * vr[0][i].w;
            p1 += v.x * vr[1][i].x + v.y * vr[1][i].y + v.z * vr[1][i].z + v.w * vr[1][i].w;
            p2 += v.x * vr[2][i].x + v.y * vr[2][i].y + v.z * vr[2][i].z + v.w * vr[2][i].w;
        }
#pragma unroll
        for (int off = 1; off < 8; off <<= 1) {
            p0 += __shfl_xor(p0, off);
            p1 += __shfl_xor(p1, off);
            p2 += __shfl_xor(p2, off);
        }
        if (sub == 0) {
            int d = dst[e];
            int p = atomicSub(&cnt[d], 1) - 1;
            int q = rowptr[d] + p;
            u32x4 r;
            r.x = (uint32_t)src[e];
            r.y = __float_as_uint(p0);
            r.z = __float_as_uint(p1);
            r.w = __float_as_uint(p2);
            __builtin_nontemporal_store(r, (u32x4*)&rec[(size_t)q * 4]);
        }
    }
}

// ---------------- standalone gemm for layers 1,2 (bf16 A) ----------------

__global__ __launch_bounds__(256) void gemm_mfma_k(const uint16_t* __restrict__ A,
                                                   const uint16_t* __restrict__ Wt,
                                                   const float* __restrict__ as_,
                                                   const float* __restrict__ ad_,
                                                   uint16_t* __restrict__ hbf,
                                                   float* __restrict__ hs, float* __restrict__ hd, int N) {
    __shared__ uint4 As[64 * 16];
    gemm_body(As, blockIdx.x, threadIdx.x, A, nullptr, Wt, as_, ad_, hbf, hs, hd, N);
}

// ---------------- fused softmax + aggregate + bias + LayerNorm ----------------
// Fast path (ne<=32): NO LDS. col_j / alpha_j broadcast via v_readlane -> SGPR;
// gathers use scalar row base + lane offset (saddr form). Cuts ~40% of node VALU.

__global__ __launch_bounds__(256) void node_k(const uint32_t* __restrict__ hb, const float* __restrict__ hs,
                                              const float* __restrict__ hd, const uint4* __restrict__ rec,
                                              const int* __restrict__ rowptr,
                                              const float* __restrict__ bias, const float* __restrict__ gamma,
                                              const float* __restrict__ beta,
                                              uint32_t* __restrict__ outb, float* __restrict__ outf,
                                              int N, int lsel) {
    __shared__ float s_al[4][66];
    __shared__ int s_co[4][66];
    int w = threadIdx.x >> 6;
    int lane = threadIdx.x & 63;
    int wid = blockIdx.x * 4 + w;
    if (wid >= N) return;
    int beg = rowptr[wid], end = rowptr[wid + 1];
    int deg = end - beg;
    float hdi = hd[wid];
    float hsi = hs[wid];
    f32x2 acc2 = {0.f, 0.f};

    if (deg <= 63) {
        int ne = deg + 1;
        bool v = lane < deg;
        uint4 r = v ? rec[beg + lane] : make_uint4(0u, 0u, 0u, 0u);
        int col = (int)r.x;
        uint32_t ecu = lsel == 0 ? r.y : (lsel == 1 ? r.z : r.w);
        float ec = __uint_as_float(ecu);
        float hsc = v ? hs[col] : 0.f;

        if (ne <= 32) {
            // ---- register prefetch: scalar (readlane) row ids, uniform-base gathers ----
            uint32_t rb[4][8];
#pragma unroll
            for (int g = 0; g < 4; ++g) {
                if (g * 8 < ne) {
#pragma unroll
                    for (int j0 = 0; j0 < 8; ++j0) {
                        int c = __builtin_amdgcn_readlane(col, g * 8 + j0);
                        rb[g][j0] = hb[((size_t)(uint32_t)c << 6) + lane];
                    }
                }
            }
            // ---- softmax (overlaps in-flight gathers) ----
            float a = v ? (hsc + hdi + ec) : -3e38f;
            a = a > 0.f ? a : 0.2f * a;
            float sumec = wred_sum(v ? ec : 0.f);
            float ecs = deg > 0 ? sumec / (float)deg : 0.f;
            float as_ = hsi + hdi + ecs;
            as_ = as_ > 0.f ? as_ : 0.2f * as_;
            float m = fmaxf(wred_max(a), as_);
            float p = __expf(a - m);       // 0 for invalid lanes
            float ps = __expf(as_ - m);    // uniform across wave
            float denom = wred_sum(p) + ps;
            float inv = 1.f / denom;
            float pinv = p * inv;          // lane j holds alpha_j
            float alS = ps * inv;          // uniform
            // ---- aggregate: alpha via readlane (scalar FMA operand) ----
#pragma unroll
            for (int g = 0; g < 4; ++g) {
                if (g * 8 < ne) {
#pragma unroll
                    for (int j0 = 0; j0 < 8; ++j0) {
                        float al = __uint_as_float(
                            (uint32_t)__builtin_amdgcn_readlane(__float_as_uint(pinv), g * 8 + j0));
                        uint32_t b = rb[g][j0];
                        f32x2 hv;
                        hv.x = __uint_as_float(b << 16);
                        hv.y = __uint_as_float(b & 0xffff0000u);
                        acc2 += hv * al;
                    }
                }
            }
            // self loop
            uint32_t b = hb[((size_t)(uint32_t)wid << 6) + lane];
            f32x2 hS; hS.x = __uint_as_float(b << 16); hS.y = __uint_as_float(b & 0xffff0000u);
            acc2 += hS * alS;
        } else {
            // medium path (32 < deg <= 63): LDS broadcast
            s_co[w][lane] = col;
            if (lane == 0) { s_co[w][deg] = wid; }
            float a = v ? (hsc + hdi + ec) : -3e38f;
            a = a > 0.f ? a : 0.2f * a;
            float sumec = wred_sum(v ? ec : 0.f);
            float ecs = sumec / (float)deg;
            float as_ = hsi + hdi + ecs;
            as_ = as_ > 0.f ? as_ : 0.2f * as_;
            float m = fmaxf(wred_max(a), as_);
            float p = __expf(a - m);
            float ps = __expf(as_ - m);
            float denom = wred_sum(p) + ps;
            float inv = 1.f / denom;
            s_al[w][lane] = p * inv;
            if (lane == 0) { s_al[w][deg] = ps * inv; }
            __asm__ volatile("s_waitcnt lgkmcnt(0)" ::: "memory");
            int j = 0;
            for (; j + 4 <= ne; j += 4) {
                int c0 = s_co[w][j], c1 = s_co[w][j + 1], c2 = s_co[w][j + 2], c3 = s_co[w][j + 3];
                float a0 = s_al[w][j], a1 = s_al[w][j + 1], a2 = s_al[w][j + 2], a3 = s_al[w][j + 3];
                uint32_t b0 = hb[(size_t)c0 * 64 + lane];
                uint32_t b1 = hb[(size_t)c1 * 64 + lane];
                uint32_t b2 = hb[(size_t)c2 * 64 + lane];
                uint32_t b3 = hb[(size_t)c3 * 64 + lane];
                f32x2 h0; h0.x = __uint_as_float(b0 << 16); h0.y = __uint_as_float(b0 & 0xffff0000u);
                f32x2 h1; h1.x = __uint_as_float(b1 << 16); h1.y = __uint_as_float(b1 & 0xffff0000u);
                f32x2 h2; h2.x = __uint_as_float(b2 << 16); h2.y = __uint_as_float(b2 & 0xffff0000u);
                f32x2 h3; h3.x = __uint_as_float(b3 << 16); h3.y = __uint_as_float(b3 & 0xffff0000u);
                acc2 += h0 * a0 + h1 * a1 + h2 * a2 + h3 * a3;
            }
            for (; j < ne; ++j) {
                int c0 = s_co[w][j];
                float a0 = s_al[w][j];
                uint32_t b0 = hb[(size_t)c0 * 64 + lane];
                f32x2 h0; h0.x = __uint_as_float(b0 << 16); h0.y = __uint_as_float(b0 & 0xffff0000u);
                acc2 += h0 * a0;
            }
        }
    } else {
        float m = -3e38f, dsum = 0.f, sumec = 0.f;
        for (int base = 0; base < deg; base += 64) {
            int jj = base + lane;
            bool v = jj < deg;
            uint4 r = v ? rec[beg + jj] : make_uint4(0u, 0u, 0u, 0u);
            uint32_t ecu = lsel == 0 ? r.y : (lsel == 1 ? r.z : r.w);
            float ec = __uint_as_float(ecu);
            float a = v ? (hs[(int)r.x] + hdi + ec) : -3e38f;
            a = a > 0.f ? a : 0.2f * a;
            sumec += wred_sum(v ? ec : 0.f);
            float cm = wred_max(a);
            float nm = fmaxf(m, cm);
            dsum = dsum * __expf(m - nm) + wred_sum(__expf(a - nm));
            m = nm;
        }
        float ecs = sumec / (float)deg;
        float as_ = hsi + hdi + ecs;
        as_ = as_ > 0.f ? as_ : 0.2f * as_;
        float nm = fmaxf(m, as_);
        dsum = dsum * __expf(m - nm) + __expf(as_ - nm);
        m = nm;
        float inv = 1.f / dsum;
        for (int base = 0; base < deg; base += 64) {
            int jj = base + lane;
            bool v = jj < deg;
            uint4 r = v ? rec[beg + jj] : make_uint4(0u, 0u, 0u, 0u);
            int col = (int)r.x;
            uint32_t ecu = lsel == 0 ? r.y : (lsel == 1 ? r.z : r.w);
            float ec = __uint_as_float(ecu);
            float a = v ? (hs[col] + hdi + ec) : -3e38f;
            a = a > 0.f ? a : 0.2f * a;
            __asm__ volatile("s_waitcnt lgkmcnt(0)" ::: "memory");
            s_al[w][lane] = __expf(a - m) * inv;
            s_co[w][lane] = col;
            __asm__ volatile("s_waitcnt lgkmcnt(0)" ::: "memory");
            int cnt2 = min(64, deg - base);
            for (int k = 0; k < cnt2; ++k) {
                int c = s_co[w][k];
                float al = s_al[w][k];
                uint32_t b = hb[(size_t)c * 64 + lane];
                f32x2 h0; h0.x = __uint_as_float(b << 16); h0.y = __uint_as_float(b & 0xffff0000u);
                acc2 += h0 * al;
            }
        }
        float alS = __expf(as_ - m) * inv;
        uint32_t b = hb[(size_t)wid * 64 + lane];
        f32x2 hS; hS.x = __uint_as_float(b << 16); hS.y = __uint_as_float(b & 0xffff0000u);
        acc2 += hS * alS;
    }

    float2 bi = *(const float2*)&bias[lane * 2];
    float o0 = acc2.x + bi.x, o1 = acc2.y + bi.y;
    float mean = wred_sum(o0 + o1) * (1.f / 128.f);
    float d0 = o0 - mean, d1 = o1 - mean;
    float var = wred_sum(d0 * d0 + d1 * d1) * (1.f / 128.f);
    float rstd = rsqrtf(var + 1e-5f);
    float2 g = *(const float2*)&gamma[lane * 2];
    float2 be = *(const float2*)&beta[lane * 2];
    float2 o;
    o.x = d0 * rstd * g.x + be.x;
    o.y = d1 * rstd * g.y + be.y;
    if (outf) {
        *(float2*)&outf[(size_t)wid * D + lane * 2] = o;
    } else {
        outb[(size_t)wid * 64 + lane] = f2bf_rne(o.x) | (f2bf_rne(o.y) << 16);
    }
}

// ---------------- launch ----------------

extern "C" void kernel_launch(void* const* d_in, const int* in_sizes, int n_in,
                              void* d_out, int out_size, void* d_ws, size_t ws_size,
                              hipStream_t stream) {
    const float* x = (const float*)d_in[0];
    const int* ei = (const int*)d_in[1];
    const float* ea = (const float*)d_in[2];
    const float* W = (const float*)d_in[3];
    const float* att_src = (const float*)d_in[4];
    const float* att_dst = (const float*)d_in[5];
    const float* We = (const float*)d_in[6];
    const float* att_edge = (const float*)d_in[7];
    const float* bias = (const float*)d_in[8];
    const float* gamma = (const float*)d_in[9];
    const float* beta = (const float*)d_in[10];

    int N = in_sizes[0] / D;
    int E = in_sizes[1] / 2;
    const int* srcA = ei;
    const int* dstA = ei + E;

    float* p = (float*)d_ws;
    float* hsb = p;   p += N;
    float* hdb = p;   p += N;
    float* vbuf = p;  p += LNUM * D + 128;
    uint16_t* hbf = (uint16_t*)p;
    uint16_t* hnb = hbf + (size_t)N * D;
    uint16_t* Wt = hnb + (size_t)N * D;
    uint4* rec = (uint4*)(Wt + (size_t)LNUM * D * D);
    int* ip = (int*)(rec + E);
    int* rowptr = ip; ip += N + 1;
    int* cnt = ip;    ip += N;

    hipMemsetAsync(cnt, 0, sizeof(int) * N, stream);
    pre_k<<<1024, 256, 0, stream>>>(W, We, att_edge, dstA, Wt, vbuf, cnt, E);
    scan_k<<<1, 1024, 0, stream>>>(cnt, rowptr, N);

    int NB_G = (N + 63) / 64;
    int NB_F = (E + 31) / 32;
    fg_k<<<NB_G + NB_F, 256, 0, stream>>>(x, Wt, att_src, att_dst, hbf, hsb, hdb, N,
                                          ea, vbuf, srcA, dstA, rowptr, cnt, (uint32_t*)rec, E, NB_G);
    node_k<<<(N + 3) / 4, 256, 0, stream>>>((const uint32_t*)hbf, hsb, hdb, rec, rowptr,
                                            bias, gamma, beta, (uint32_t*)hnb, nullptr, N, 0);

    const uint16_t* hin = hnb;
    for (int l = 1; l < LNUM; ++l) {
        gemm_mfma_k<<<(N + 63) / 64, 256, 0, stream>>>(hin, Wt + (size_t)l * D * D,
                                                       att_src + (size_t)l * D, att_dst + (size_t)l * D,
                                                       hbf, hsb, hdb, N);
        bool last = (l == LNUM - 1);
        node_k<<<(N + 3) / 4, 256, 0, stream>>>((const uint32_t*)hbf, hsb, hdb, rec, rowptr,
                                                bias + (size_t)l * D, gamma + (size_t)l * D,
                                                beta + (size_t)l * D,
                                                last ? nullptr : (uint32_t*)hnb,
                                                last ? (float*)d_out : nullptr, N, l);
        hin = hnb;
    }
}

// Round 16
// 413.533 us; speedup vs baseline: 1.0925x; 1.0925x over previous
//
#include <hip/hip_runtime.h>
#include <cstdint>

#define D 128
#define LNUM 3

typedef short short8 __attribute__((ext_vector_type(8)));
typedef float f32x4 __attribute__((ext_vector_type(4)));
typedef float f32x2 __attribute__((ext_vector_type(2)));
typedef uint32_t u32x4 __attribute__((ext_vector_type(4)));

static __device__ __forceinline__ float wred_sum(float x) {
#pragma unroll
    for (int off = 32; off; off >>= 1) x += __shfl_xor(x, off);
    return x;
}
static __device__ __forceinline__ float wred_max(float x) {
#pragma unroll
    for (int off = 32; off; off >>= 1) x = fmaxf(x, __shfl_xor(x, off));
    return x;
}
static __device__ __forceinline__ uint32_t f2bf_rne(float x) {
    uint32_t u = __float_as_uint(x);
    uint32_t r = u + 0x7fffu + ((u >> 16) & 1u);
    return r >> 16;
}

// ---------------- pre: Wt transpose->bf16, vbuf = We@ae, hist ----------------

__global__ __launch_bounds__(256) void pre_k(const float* __restrict__ W, const float* __restrict__ We,
                                             const float* __restrict__ ae,
                                             const int* __restrict__ dst,
                                             uint16_t* __restrict__ Wt, float* __restrict__ vbuf,
                                             int* __restrict__ cnt, int E) {
    int tid = blockIdx.x * 256 + threadIdx.x;
    int stride = gridDim.x * 256;
    for (int e = tid; e < E; e += stride) atomicAdd(&cnt[dst[e]], 1);
    for (int i = tid; i < LNUM * D * D; i += stride) {
        int l = i >> 14;
        int r = i & (D * D - 1);
        int j = r >> 7, k = r & 127;
        Wt[i] = (uint16_t)f2bf_rne(W[(size_t)l * D * D + (size_t)k * D + j]);
    }
    if (tid < LNUM * D) {
        int l = tid >> 7, j = tid & 127;
        const float* Wrow = We + ((size_t)l * D + j) * D;
        const float* a = ae + (size_t)l * D;
        float s = 0.f;
        for (int d = 0; d < D; ++d) s += Wrow[d] * a[d];
        vbuf[tid] = s;
    }
}

// ---------------- exclusive scan of cnt -> rowptr ----------------

__global__ __launch_bounds__(1024) void scan_k(const int* __restrict__ cnt, int* __restrict__ rowptr, int N) {
    __shared__ int sh[1024];
    int t = threadIdx.x;
    int chunk = (N + 1023) >> 10;
    int b = t * chunk;
    int e = min(b + chunk, N);
    int s = 0;
    for (int i = b; i < e; ++i) s += cnt[i];
    sh[t] = s;
    __syncthreads();
    for (int off = 1; off < 1024; off <<= 1) {
        int v = (t >= off) ? sh[t - off] : 0;
        __syncthreads();
        sh[t] += v;
        __syncthreads();
    }
    int run = sh[t] - s;  // exclusive
    for (int i = b; i < e; ++i) { rowptr[i] = run; run += cnt[i]; }
    if (t == 1023) rowptr[N] = sh[1023];
}

// ---------------- gemm body; A either bf16 (Ab) or f32 (Af); NT stores to hbf ----------------

static __device__ __forceinline__ void gemm_body(uint4* As, int bid, int t,
                                                 const uint16_t* __restrict__ Ab,
                                                 const float* __restrict__ Af,
                                                 const uint16_t* __restrict__ Wt,
                                                 const float* __restrict__ as_,
                                                 const float* __restrict__ ad_,
                                                 uint16_t* __restrict__ hbf,
                                                 float* __restrict__ hs, float* __restrict__ hd, int N) {
    int row0 = bid * 64;
    if (Af) {
#pragma unroll
        for (int it = 0; it < 4; ++it) {
            int idx2 = it * 256 + t;
            int r = idx2 >> 4, s = idx2 & 15;
            int gr = row0 + r;
            uint4 o = make_uint4(0u, 0u, 0u, 0u);
            if (gr < N) {
                float4 v0 = *(const float4*)&Af[(size_t)gr * D + s * 8];
                float4 v1 = *(const float4*)&Af[(size_t)gr * D + s * 8 + 4];
                o.x = f2bf_rne(v0.x) | (f2bf_rne(v0.y) << 16);
                o.y = f2bf_rne(v0.z) | (f2bf_rne(v0.w) << 16);
                o.z = f2bf_rne(v1.x) | (f2bf_rne(v1.y) << 16);
                o.w = f2bf_rne(v1.z) | (f2bf_rne(v1.w) << 16);
            }
            As[r * 16 + (s ^ (r & 7))] = o;
        }
    } else {
#pragma unroll
        for (int it = 0; it < 4; ++it) {
            int idx2 = it * 256 + t;
            int r = idx2 >> 4, s = idx2 & 15;
            int gr = row0 + r;
            uint4 v = make_uint4(0u, 0u, 0u, 0u);
            if (gr < N) v = *(const uint4*)&Ab[(size_t)gr * D + s * 8];
            As[r * 16 + (s ^ (r & 7))] = v;
        }
    }
    __syncthreads();
    int w = t >> 6, l = t & 63;
    int lrow = l & 15, lk = l >> 4;
    int rbase = w * 16;
    short8 afrag[4];
#pragma unroll
    for (int ks = 0; ks < 4; ++ks) {
        int r = rbase + lrow;
        int s = (ks * 4 + lk) ^ (r & 7);
        afrag[ks] = __builtin_bit_cast(short8, As[r * 16 + s]);
    }
    float psum[4] = {0.f, 0.f, 0.f, 0.f}, pdum[4] = {0.f, 0.f, 0.f, 0.f};
#pragma unroll
    for (int ct = 0; ct < 8; ++ct) {
        f32x4 acc = {0.f, 0.f, 0.f, 0.f};
#pragma unroll
        for (int ks = 0; ks < 4; ++ks) {
            short8 b = *(const short8*)&Wt[(size_t)(ct * 16 + lrow) * D + ks * 32 + lk * 8];
            acc = __builtin_amdgcn_mfma_f32_16x16x32_bf16(afrag[ks], b, acc, 0, 0, 0);
        }
        int col_g = ct * 16 + lrow;
        float av = as_[col_g], dv = ad_[col_g];
#pragma unroll
        for (int r = 0; r < 4; ++r) {
            float v = acc[r];
            psum[r] += v * av;
            pdum[r] += v * dv;
            int row_g = row0 + rbase + lk * 4 + r;
            if (row_g < N)
                __builtin_nontemporal_store((uint16_t)f2bf_rne(v), &hbf[(size_t)row_g * D + col_g]);
        }
    }
#pragma unroll
    for (int r = 0; r < 4; ++r) {
        float ps = psum[r], pd = pdum[r];
#pragma unroll
        for (int off = 1; off < 16; off <<= 1) {
            ps += __shfl_xor(ps, off);
            pd += __shfl_xor(pd, off);
        }
        if (lrow == 0) {
            int row_g = row0 + rbase + lk * 4 + r;
            if (row_g < N) { hs[row_g] = ps; hd[row_g] = pd; }
        }
    }
}

// ---------------- merged: gemm0 (f32 A, blocks < NB_G) + fillec (rest) ----------------

__global__ __launch_bounds__(256) void fg_k(const float* __restrict__ x, const uint16_t* __restrict__ Wt,
                                            const float* __restrict__ as_, const float* __restrict__ ad_,
                                            uint16_t* __restrict__ hbf, float* __restrict__ hs,
                                            float* __restrict__ hd, int N,
                                            const float* __restrict__ ea, const float* __restrict__ vbuf,
                                            const int* __restrict__ src, const int* __restrict__ dst,
                                            const int* __restrict__ rowptr, int* __restrict__ cnt,
                                            uint32_t* __restrict__ rec, int E, int NB_G) {
    __shared__ uint4 As[64 * 16];
    int t = threadIdx.x;
    if ((int)blockIdx.x < NB_G) {
        gemm_body(As, blockIdx.x, t, nullptr, x, Wt, as_, ad_, hbf, hs, hd, N);
        return;
    }
    int bid = blockIdx.x - NB_G;
    int nbF = gridDim.x - NB_G;
    int sub = t & 7;
    float4 vr[3][4];
#pragma unroll
    for (int l = 0; l < 3; ++l)
#pragma unroll
        for (int i = 0; i < 4; ++i)
            vr[l][i] = *(const float4*)&vbuf[l * D + sub * 16 + i * 4];

    for (int e0 = bid * 32; e0 < E; e0 += nbF * 32) {
        int e = e0 + (t >> 3);
        if (e >= E) continue;
        const float* row = ea + (size_t)e * D + sub * 16;
        float p0 = 0.f, p1 = 0.f, p2 = 0.f;
#pragma unroll
        for (int i = 0; i < 4; ++i) {
            float4 v = *(const float4*)&row[i * 4];
            p0 += v.x * vr[0][i].x + v.y * vr[0][i].y + v.z * vr[0][i].z + v.w * vr[0][i].w;
            p1 += v.x * vr[1][i].x + v.y * vr[1][i].y + v.z * vr[1][i].z + v.w * vr[1][i].w;
            p2 += v.x * vr[2][i].x + v.y * vr[2][i].y + v.z * vr[2][i].z + v.w * vr[2][i].w;
        }
#pragma unroll
        for (int off = 1; off < 8; off <<= 1) {
            p0 += __shfl_xor(p0, off);
            p1 += __shfl_xor(p1, off);
            p2 += __shfl_xor(p2, off);
        }
        if (sub == 0) {
            int d = dst[e];
            int p = atomicSub(&cnt[d], 1) - 1;
            int q = rowptr[d] + p;
            u32x4 r;
            r.x = (uint32_t)src[e];
            r.y = __float_as_uint(p0);
            r.z = __float_as_uint(p1);
            r.w = __float_as_uint(p2);
            __builtin_nontemporal_store(r, (u32x4*)&rec[(size_t)q * 4]);
        }
    }
}

// ---------------- standalone gemm for layers 1,2 (bf16 A) ----------------

__global__ __launch_bounds__(256) void gemm_mfma_k(const uint16_t* __restrict__ A,
                                                   const uint16_t* __restrict__ Wt,
                                                   const float* __restrict__ as_,
                                                   const float* __restrict__ ad_,
                                                   uint16_t* __restrict__ hbf,
                                                   float* __restrict__ hs, float* __restrict__ hd, int N) {
    __shared__ uint4 As[64 * 16];
    gemm_body(As, blockIdx.x, threadIdx.x, A, nullptr, Wt, as_, ad_, hbf, hs, hd, N);
}

// ---------------- fused softmax + aggregate + bias + LayerNorm ----------------

__global__ __launch_bounds__(256) void node_k(const uint32_t* __restrict__ hb, const float* __restrict__ hs,
                                              const float* __restrict__ hd, const uint4* __restrict__ rec,
                                              const int* __restrict__ rowptr,
                                              const float* __restrict__ bias, const float* __restrict__ gamma,
                                              const float* __restrict__ beta,
                                              uint32_t* __restrict__ outb, float* __restrict__ outf,
                                              int N, int lsel) {
    __shared__ float s_al[4][66];
    __shared__ int s_co[4][66];
    int w = threadIdx.x >> 6;
    int lane = threadIdx.x & 63;
    int wid = blockIdx.x * 4 + w;
    if (wid >= N) return;
    int beg = rowptr[wid], end = rowptr[wid + 1];
    int deg = end - beg;
    float hdi = hd[wid];
    float hsi = hs[wid];
    f32x2 acc2 = {0.f, 0.f};

    if (deg <= 63) {
        int ne = deg + 1;
        bool v = lane < deg;
        uint4 r = v ? rec[beg + lane] : make_uint4(0u, 0u, 0u, 0u);
        int col = (int)r.x;
        uint32_t ecu = lsel == 0 ? r.y : (lsel == 1 ? r.z : r.w);
        float ec = __uint_as_float(ecu);
        float hsc = v ? hs[col] : 0.f;
        s_co[w][lane] = col;
        if (lane == 0) { s_co[w][deg] = wid; }
        __asm__ volatile("s_waitcnt lgkmcnt(0)" ::: "memory");

        uint32_t rb[4][8];
        bool fast = ne <= 32;
        if (fast) {
#pragma unroll
            for (int g = 0; g < 4; ++g) {
                if (g * 8 < ne) {
#pragma unroll
                    for (int j0 = 0; j0 < 8; ++j0) {
                        int c = s_co[w][g * 8 + j0];
                        rb[g][j0] = hb[(size_t)c * 64 + lane];
                    }
                }
            }
        }

        float a = v ? (hsc + hdi + ec) : -3e38f;
        a = a > 0.f ? a : 0.2f * a;
        float sumec = wred_sum(v ? ec : 0.f);
        float ecs = deg > 0 ? sumec / (float)deg : 0.f;
        float as_ = hsi + hdi + ecs;
        as_ = as_ > 0.f ? as_ : 0.2f * as_;
        float m = fmaxf(wred_max(a), as_);
        float p = __expf(a - m);
        float ps = __expf(as_ - m);
        float denom = wred_sum(p) + ps;
        float inv = 1.f / denom;
        s_al[w][lane] = p * inv;
        if (lane == 0) { s_al[w][deg] = ps * inv; }
        __asm__ volatile("s_waitcnt lgkmcnt(0)" ::: "memory");

        if (fast) {
#pragma unroll
            for (int g = 0; g < 4; ++g) {
                if (g * 8 < ne) {
#pragma unroll
                    for (int j0 = 0; j0 < 8; ++j0) {
                        float al = s_al[w][g * 8 + j0];
                        uint32_t b = rb[g][j0];
                        f32x2 hv;
                        hv.x = __uint_as_float(b << 16);
                        hv.y = __uint_as_float(b & 0xffff0000u);
                        acc2 += hv * al;
                    }
                }
            }
        } else {
            int j = 0;
            for (; j + 4 <= ne; j += 4) {
                int c0 = s_co[w][j], c1 = s_co[w][j + 1], c2 = s_co[w][j + 2], c3 = s_co[w][j + 3];
                float a0 = s_al[w][j], a1 = s_al[w][j + 1], a2 = s_al[w][j + 2], a3 = s_al[w][j + 3];
                uint32_t b0 = hb[(size_t)c0 * 64 + lane];
                uint32_t b1 = hb[(size_t)c1 * 64 + lane];
                uint32_t b2 = hb[(size_t)c2 * 64 + lane];
                uint32_t b3 = hb[(size_t)c3 * 64 + lane];
                f32x2 h0; h0.x = __uint_as_float(b0 << 16); h0.y = __uint_as_float(b0 & 0xffff0000u);
                f32x2 h1; h1.x = __uint_as_float(b1 << 16); h1.y = __uint_as_float(b1 & 0xffff0000u);
                f32x2 h2; h2.x = __uint_as_float(b2 << 16); h2.y = __uint_as_float(b2 & 0xffff0000u);
                f32x2 h3; h3.x = __uint_as_float(b3 << 16); h3.y = __uint_as_float(b3 & 0xffff0000u);
                acc2 += h0 * a0 + h1 * a1 + h2 * a2 + h3 * a3;
            }
            for (; j < ne; ++j) {
                int c0 = s_co[w][j];
                float a0 = s_al[w][j];
                uint32_t b0 = hb[(size_t)c0 * 64 + lane];
                f32x2 h0; h0.x = __uint_as_float(b0 << 16); h0.y = __uint_as_float(b0 & 0xffff0000u);
                acc2 += h0 * a0;
            }
        }
    } else {
        float m = -3e38f, dsum = 0.f, sumec = 0.f;
        for (int base = 0; base < deg; base += 64) {
            int jj = base + lane;
            bool v = jj < deg;
            uint4 r = v ? rec[beg + jj] : make_uint4(0u, 0u, 0u, 0u);
            uint32_t ecu = lsel == 0 ? r.y : (lsel == 1 ? r.z : r.w);
            float ec = __uint_as_float(ecu);
            float a = v ? (hs[(int)r.x] + hdi + ec) : -3e38f;
            a = a > 0.f ? a : 0.2f * a;
            sumec += wred_sum(v ? ec : 0.f);
            float cm = wred_max(a);
            float nm = fmaxf(m, cm);
            dsum = dsum * __expf(m - nm) + wred_sum(__expf(a - nm));
            m = nm;
        }
        float ecs = sumec / (float)deg;
        float as_ = hsi + hdi + ecs;
        as_ = as_ > 0.f ? as_ : 0.2f * as_;
        float nm = fmaxf(m, as_);
        dsum = dsum * __expf(m - nm) + __expf(as_ - nm);
        m = nm;
        float inv = 1.f / dsum;
        for (int base = 0; base < deg; base += 64) {
            int jj = base + lane;
            bool v = jj < deg;
            uint4 r = v ? rec[beg + jj] : make_uint4(0u, 0u, 0u, 0u);
            int col = (int)r.x;
            uint32_t ecu = lsel == 0 ? r.y : (lsel == 1 ? r.z : r.w);
            float ec = __uint_as_float(ecu);
            float a = v ? (hs[col] + hdi + ec) : -3e38f;
            a = a > 0.f ? a : 0.2f * a;
            __asm__ volatile("s_waitcnt lgkmcnt(0)" ::: "memory");
            s_al[w][lane] = __expf(a - m) * inv;
            s_co[w][lane] = col;
            __asm__ volatile("s_waitcnt lgkmcnt(0)" ::: "memory");
            int cnt2 = min(64, deg - base);
            for (int k = 0; k < cnt2; ++k) {
                int c = s_co[w][k];
                float al = s_al[w][k];
                uint32_t b = hb[(size_t)c * 64 + lane];
                f32x2 h0; h0.x = __uint_as_float(b << 16); h0.y = __uint_as_float(b & 0xffff0000u);
                acc2 += h0 * al;
            }
        }
        float alS = __expf(as_ - m) * inv;
        uint32_t b = hb[(size_t)wid * 64 + lane];
        f32x2 hS; hS.x = __uint_as_float(b << 16); hS.y = __uint_as_float(b & 0xffff0000u);
        acc2 += hS * alS;
    }

    float2 bi = *(const float2*)&bias[lane * 2];
    float o0 = acc2.x + bi.x, o1 = acc2.y + bi.y;
    float mean = wred_sum(o0 + o1) * (1.f / 128.f);
    float d0 = o0 - mean, d1 = o1 - mean;
    float var = wred_sum(d0 * d0 + d1 * d1) * (1.f / 128.f);
    float rstd = rsqrtf(var + 1e-5f);
    float2 g = *(const float2*)&gamma[lane * 2];
    float2 be = *(const float2*)&beta[lane * 2];
    float2 o;
    o.x = d0 * rstd * g.x + be.x;
    o.y = d1 * rstd * g.y + be.y;
    if (outf) {
        *(float2*)&outf[(size_t)wid * D + lane * 2] = o;
    } else {
        outb[(size_t)wid * 64 + lane] = f2bf_rne(o.x) | (f2bf_rne(o.y) << 16);
    }
}

// ---------------- launch ----------------

extern "C" void kernel_launch(void* const* d_in, const int* in_sizes, int n_in,
                              void* d_out, int out_size, void* d_ws, size_t ws_size,
                              hipStream_t stream) {
    const float* x = (const float*)d_in[0];
    const int* ei = (const int*)d_in[1];
    const float* ea = (const float*)d_in[2];
    const float* W = (const float*)d_in[3];
    const float* att_src = (const float*)d_in[4];
    const float* att_dst = (const float*)d_in[5];
    const float* We = (const float*)d_in[6];
    const float* att_edge = (const float*)d_in[7];
    const float* bias = (const float*)d_in[8];
    const float* gamma = (const float*)d_in[9];
    const float* beta = (const float*)d_in[10];

    int N = in_sizes[0] / D;
    int E = in_sizes[1] / 2;
    const int* srcA = ei;
    const int* dstA = ei + E;

    float* p = (float*)d_ws;
    float* hsb = p;   p += N;
    float* hdb = p;   p += N;
    float* vbuf = p;  p += LNUM * D + 128;
    uint16_t* hbf = (uint16_t*)p;
    uint16_t* hnb = hbf + (size_t)N * D;
    uint16_t* Wt = hnb + (size_t)N * D;
    uint4* rec = (uint4*)(Wt + (size_t)LNUM * D * D);
    int* ip = (int*)(rec + E);
    int* rowptr = ip; ip += N + 1;
    int* cnt = ip;    ip += N;

    hipMemsetAsync(cnt, 0, sizeof(int) * N, stream);
    pre_k<<<1024, 256, 0, stream>>>(W, We, att_edge, dstA, Wt, vbuf, cnt, E);
    scan_k<<<1, 1024, 0, stream>>>(cnt, rowptr, N);

    int NB_G = (N + 63) / 64;
    int NB_F = (E + 31) / 32;
    fg_k<<<NB_G + NB_F, 256, 0, stream>>>(x, Wt, att_src, att_dst, hbf, hsb, hdb, N,
                                          ea, vbuf, srcA, dstA, rowptr, cnt, (uint32_t*)rec, E, NB_G);
    node_k<<<(N + 3) / 4, 256, 0, stream>>>((const uint32_t*)hbf, hsb, hdb, rec, rowptr,
                                            bias, gamma, beta, (uint32_t*)hnb, nullptr, N, 0);

    const uint16_t* hin = hnb;
    for (int l = 1; l < LNUM; ++l) {
        gemm_mfma_k<<<(N + 63) / 64, 256, 0, stream>>>(hin, Wt + (size_t)l * D * D,
                                                       att_src + (size_t)l * D, att_dst + (size_t)l * D,
                                                       hbf, hsb, hdb, N);
        bool last = (l == LNUM - 1);
        node_k<<<(N + 3) / 4, 256, 0, stream>>>((const uint32_t*)hbf, hsb, hdb, rec, rowptr,
                                                bias + (size_t)l * D, gamma + (size_t)l * D,
                                                beta + (size_t)l * D,
                                                last ? nullptr : (uint32_t*)hnb,
                                                last ? (float*)d_out : nullptr, N, l);
        hin = hnb;
    }
}

// Round 18
// 412.485 us; speedup vs baseline: 1.0953x; 1.0025x over previous
//
#include <hip/hip_runtime.h>
#include <cstdint>

#define D 128
#define LNUM 3

typedef short short8 __attribute__((ext_vector_type(8)));
typedef float f32x4 __attribute__((ext_vector_type(4)));
typedef float f32x2 __attribute__((ext_vector_type(2)));
typedef uint32_t u32x4 __attribute__((ext_vector_type(4)));

static __device__ __forceinline__ float wred_sum(float x) {
#pragma unroll
    for (int off = 32; off; off >>= 1) x += __shfl_xor(x, off);
    return x;
}
static __device__ __forceinline__ float wred_max(float x) {
#pragma unroll
    for (int off = 32; off; off >>= 1) x = fmaxf(x, __shfl_xor(x, off));
    return x;
}
static __device__ __forceinline__ uint32_t f2bf_rne(float x) {
    uint32_t u = __float_as_uint(x);
    uint32_t r = u + 0x7fffu + ((u >> 16) & 1u);
    return r >> 16;
}

// ---------------- pre: Wt transpose->bf16, vbuf = We@ae, hist ----------------

__global__ __launch_bounds__(256) void pre_k(const float* __restrict__ W, const float* __restrict__ We,
                                             const float* __restrict__ ae,
                                             const int* __restrict__ dst,
                                             uint16_t* __restrict__ Wt, float* __restrict__ vbuf,
                                             int* __restrict__ cnt, int E) {
    int tid = blockIdx.x * 256 + threadIdx.x;
    int stride = gridDim.x * 256;
    for (int e = tid; e < E; e += stride) atomicAdd(&cnt[dst[e]], 1);
    for (int i = tid; i < LNUM * D * D; i += stride) {
        int l = i >> 14;
        int r = i & (D * D - 1);
        int j = r >> 7, k = r & 127;
        Wt[i] = (uint16_t)f2bf_rne(W[(size_t)l * D * D + (size_t)k * D + j]);
    }
    if (tid < LNUM * D) {
        int l = tid >> 7, j = tid & 127;
        const float* Wrow = We + ((size_t)l * D + j) * D;
        const float* a = ae + (size_t)l * D;
        float s = 0.f;
        for (int d = 0; d < D; ++d) s += Wrow[d] * a[d];
        vbuf[tid] = s;
    }
}

// ---------------- exclusive scan of cnt -> rowptr ----------------

__global__ __launch_bounds__(1024) void scan_k(const int* __restrict__ cnt, int* __restrict__ rowptr, int N) {
    __shared__ int sh[1024];
    int t = threadIdx.x;
    int chunk = (N + 1023) >> 10;
    int b = t * chunk;
    int e = min(b + chunk, N);
    int s = 0;
    for (int i = b; i < e; ++i) s += cnt[i];
    sh[t] = s;
    __syncthreads();
    for (int off = 1; off < 1024; off <<= 1) {
        int v = (t >= off) ? sh[t - off] : 0;
        __syncthreads();
        sh[t] += v;
        __syncthreads();
    }
    int run = sh[t] - s;  // exclusive
    for (int i = b; i < e; ++i) { rowptr[i] = run; run += cnt[i]; }
    if (t == 1023) rowptr[N] = sh[1023];
}

// ---------------- gemm body; A either bf16 (Ab) or f32 (Af); NT stores to hbf ----------------

static __device__ __forceinline__ void gemm_body(uint4* As, int bid, int t,
                                                 const uint16_t* __restrict__ Ab,
                                                 const float* __restrict__ Af,
                                                 const uint16_t* __restrict__ Wt,
                                                 const float* __restrict__ as_,
                                                 const float* __restrict__ ad_,
                                                 uint16_t* __restrict__ hbf,
                                                 float* __restrict__ hs, float* __restrict__ hd, int N) {
    int row0 = bid * 64;
    if (Af) {
#pragma unroll
        for (int it = 0; it < 4; ++it) {
            int idx2 = it * 256 + t;
            int r = idx2 >> 4, s = idx2 & 15;
            int gr = row0 + r;
            uint4 o = make_uint4(0u, 0u, 0u, 0u);
            if (gr < N) {
                float4 v0 = *(const float4*)&Af[(size_t)gr * D + s * 8];
                float4 v1 = *(const float4*)&Af[(size_t)gr * D + s * 8 + 4];
                o.x = f2bf_rne(v0.x) | (f2bf_rne(v0.y) << 16);
                o.y = f2bf_rne(v0.z) | (f2bf_rne(v0.w) << 16);
                o.z = f2bf_rne(v1.x) | (f2bf_rne(v1.y) << 16);
                o.w = f2bf_rne(v1.z) | (f2bf_rne(v1.w) << 16);
            }
            As[r * 16 + (s ^ (r & 7))] = o;
        }
    } else {
#pragma unroll
        for (int it = 0; it < 4; ++it) {
            int idx2 = it * 256 + t;
            int r = idx2 >> 4, s = idx2 & 15;
            int gr = row0 + r;
            uint4 v = make_uint4(0u, 0u, 0u, 0u);
            if (gr < N) v = *(const uint4*)&Ab[(size_t)gr * D + s * 8];
            As[r * 16 + (s ^ (r & 7))] = v;
        }
    }
    __syncthreads();
    int w = t >> 6, l = t & 63;
    int lrow = l & 15, lk = l >> 4;
    int rbase = w * 16;
    short8 afrag[4];
#pragma unroll
    for (int ks = 0; ks < 4; ++ks) {
        int r = rbase + lrow;
        int s = (ks * 4 + lk) ^ (r & 7);
        afrag[ks] = __builtin_bit_cast(short8, As[r * 16 + s]);
    }
    float psum[4] = {0.f, 0.f, 0.f, 0.f}, pdum[4] = {0.f, 0.f, 0.f, 0.f};
#pragma unroll
    for (int ct = 0; ct < 8; ++ct) {
        f32x4 acc = {0.f, 0.f, 0.f, 0.f};
#pragma unroll
        for (int ks = 0; ks < 4; ++ks) {
            short8 b = *(const short8*)&Wt[(size_t)(ct * 16 + lrow) * D + ks * 32 + lk * 8];
            acc = __builtin_amdgcn_mfma_f32_16x16x32_bf16(afrag[ks], b, acc, 0, 0, 0);
        }
        int col_g = ct * 16 + lrow;
        float av = as_[col_g], dv = ad_[col_g];
#pragma unroll
        for (int r = 0; r < 4; ++r) {
            float v = acc[r];
            psum[r] += v * av;
            pdum[r] += v * dv;
            int row_g = row0 + rbase + lk * 4 + r;
            if (row_g < N)
                __builtin_nontemporal_store((uint16_t)f2bf_rne(v), &hbf[(size_t)row_g * D + col_g]);
        }
    }
#pragma unroll
    for (int r = 0; r < 4; ++r) {
        float ps = psum[r], pd = pdum[r];
#pragma unroll
        for (int off = 1; off < 16; off <<= 1) {
            ps += __shfl_xor(ps, off);
            pd += __shfl_xor(pd, off);
        }
        if (lrow == 0) {
            int row_g = row0 + rbase + lk * 4 + r;
            if (row_g < N) { hs[row_g] = ps; hd[row_g] = pd; }
        }
    }
}

// ---------------- merged: gemm0 (f32 A, blocks < NB_G) + fillec (rest) ----------------

__global__ __launch_bounds__(256) void fg_k(const float* __restrict__ x, const uint16_t* __restrict__ Wt,
                                            const float* __restrict__ as_, const float* __restrict__ ad_,
                                            uint16_t* __restrict__ hbf, float* __restrict__ hs,
                                            float* __restrict__ hd, int N,
                                            const float* __restrict__ ea, const float* __restrict__ vbuf,
                                            const int* __restrict__ src, const int* __restrict__ dst,
                                            const int* __restrict__ rowptr, int* __restrict__ cnt,
                                            uint32_t* __restrict__ rec, int E, int NB_G) {
    __shared__ uint4 As[64 * 16];
    int t = threadIdx.x;
    if ((int)blockIdx.x < NB_G) {
        gemm_body(As, blockIdx.x, t, nullptr, x, Wt, as_, ad_, hbf, hs, hd, N);
        return;
    }
    int bid = blockIdx.x - NB_G;
    int nbF = gridDim.x - NB_G;
    int sub = t & 7;
    float4 vr[3][4];
#pragma unroll
    for (int l = 0; l < 3; ++l)
#pragma unroll
        for (int i = 0; i < 4; ++i)
            vr[l][i] = *(const float4*)&vbuf[l * D + sub * 16 + i * 4];

    for (int e0 = bid * 32; e0 < E; e0 += nbF * 32) {
        int e = e0 + (t >> 3);
        if (e >= E) continue;
        const float* row = ea + (size_t)e * D + sub * 16;
        float p0 = 0.f, p1 = 0.f, p2 = 0.f;
#pragma unroll
        for (int i = 0; i < 4; ++i) {
            float4 v = *(const float4*)&row[i * 4];
            p0 += v.x * vr[0][i].x + v.y * vr[0][i].y + v.z * vr[0][i].z + v.w * vr[0][i].w;
            p1 += v.x * vr[1][i].x + v.y * vr[1][i].y + v.z * vr[1][i].z + v.w * vr[1][i].w;
            p2 += v.x * vr[2][i].x + v.y * vr[2][i].y + v.z * vr[2][i].z + v.w * vr[2][i].w;
        }
#pragma unroll
        for (int off = 1; off < 8; off <<= 1) {
            p0 += __shfl_xor(p0, off);
            p1 += __shfl_xor(p1, off);
            p2 += __shfl_xor(p2, off);
        }
        if (sub == 0) {
            int d = dst[e];
            int p = atomicSub(&cnt[d], 1) - 1;
            int q = rowptr[d] + p;
            u32x4 r;
            r.x = (uint32_t)src[e];
            r.y = __float_as_uint(p0);
            r.z = __float_as_uint(p1);
            r.w = __float_as_uint(p2);
            __builtin_nontemporal_store(r, (u32x4*)&rec[(size_t)q * 4]);
        }
    }
}

// ---------------- standalone gemm for layers 1,2 (bf16 A) ----------------

__global__ __launch_bounds__(256) void gemm_mfma_k(const uint16_t* __restrict__ A,
                                                   const uint16_t* __restrict__ Wt,
                                                   const float* __restrict__ as_,
                                                   const float* __restrict__ ad_,
                                                   uint16_t* __restrict__ hbf,
                                                   float* __restrict__ hs, float* __restrict__ hd, int N) {
    __shared__ uint4 As[64 * 16];
    gemm_body(As, blockIdx.x, threadIdx.x, A, nullptr, Wt, as_, ad_, hbf, hs, hd, N);
}

// ---------------- fused softmax + aggregate + bias + LayerNorm ----------------

__global__ __launch_bounds__(256) void node_k(const uint32_t* __restrict__ hb, const float* __restrict__ hs,
                                              const float* __restrict__ hd, const uint4* __restrict__ rec,
                                              const int* __restrict__ rowptr,
                                              const float* __restrict__ bias, const float* __restrict__ gamma,
                                              const float* __restrict__ beta,
                                              uint32_t* __restrict__ outb, float* __restrict__ outf,
                                              int N, int lsel) {
    __shared__ float s_al[4][66];
    __shared__ int s_co[4][66];
    int w = threadIdx.x >> 6;
    int lane = threadIdx.x & 63;
    int wid = blockIdx.x * 4 + w;
    if (wid >= N) return;
    int beg = rowptr[wid], end = rowptr[wid + 1];
    int deg = end - beg;
    float hdi = hd[wid];
    float hsi = hs[wid];
    f32x2 acc2 = {0.f, 0.f};

    if (deg <= 63) {
        int ne = deg + 1;
        bool v = lane < deg;
        uint4 r = v ? rec[beg + lane] : make_uint4(0u, 0u, 0u, 0u);
        int col = (int)r.x;
        uint32_t ecu = lsel == 0 ? r.y : (lsel == 1 ? r.z : r.w);
        float ec = __uint_as_float(ecu);
        float hsc = v ? hs[col] : 0.f;
        s_co[w][lane] = col;
        if (lane == 0) { s_co[w][deg] = wid; }
        __asm__ volatile("s_waitcnt lgkmcnt(0)" ::: "memory");

        uint32_t rb[4][8];
        bool fast = ne <= 32;
        if (fast) {
#pragma unroll
            for (int g = 0; g < 4; ++g) {
                if (g * 8 < ne) {
#pragma unroll
                    for (int j0 = 0; j0 < 8; ++j0) {
                        int c = s_co[w][g * 8 + j0];
                        rb[g][j0] = hb[(size_t)c * 64 + lane];
                    }
                }
            }
        }

        float a = v ? (hsc + hdi + ec) : -3e38f;
        a = a > 0.f ? a : 0.2f * a;
        float sumec = wred_sum(v ? ec : 0.f);
        float ecs = deg > 0 ? sumec / (float)deg : 0.f;
        float as_ = hsi + hdi + ecs;
        as_ = as_ > 0.f ? as_ : 0.2f * as_;
        float m = fmaxf(wred_max(a), as_);
        float p = __expf(a - m);
        float ps = __expf(as_ - m);
        float denom = wred_sum(p) + ps;
        float inv = 1.f / denom;
        s_al[w][lane] = p * inv;
        if (lane == 0) { s_al[w][deg] = ps * inv; }
        __asm__ volatile("s_waitcnt lgkmcnt(0)" ::: "memory");

        if (fast) {
#pragma unroll
            for (int g = 0; g < 4; ++g) {
                if (g * 8 < ne) {
#pragma unroll
                    for (int j0 = 0; j0 < 8; ++j0) {
                        float al = s_al[w][g * 8 + j0];
                        uint32_t b = rb[g][j0];
                        f32x2 hv;
                        hv.x = __uint_as_float(b << 16);
                        hv.y = __uint_as_float(b & 0xffff0000u);
                        acc2 += hv * al;
                    }
                }
            }
        } else {
            int j = 0;
            for (; j + 4 <= ne; j += 4) {
                int c0 = s_co[w][j], c1 = s_co[w][j + 1], c2 = s_co[w][j + 2], c3 = s_co[w][j + 3];
                float a0 = s_al[w][j], a1 = s_al[w][j + 1], a2 = s_al[w][j + 2], a3 = s_al[w][j + 3];
                uint32_t b0 = hb[(size_t)c0 * 64 + lane];
                uint32_t b1 = hb[(size_t)c1 * 64 + lane];
                uint32_t b2 = hb[(size_t)c2 * 64 + lane];
                uint32_t b3 = hb[(size_t)c3 * 64 + lane];
                f32x2 h0; h0.x = __uint_as_float(b0 << 16); h0.y = __uint_as_float(b0 & 0xffff0000u);
                f32x2 h1; h1.x = __uint_as_float(b1 << 16); h1.y = __uint_as_float(b1 & 0xffff0000u);
                f32x2 h2; h2.x = __uint_as_float(b2 << 16); h2.y = __uint_as_float(b2 & 0xffff0000u);
                f32x2 h3; h3.x = __uint_as_float(b3 << 16); h3.y = __uint_as_float(b3 & 0xffff0000u);
                acc2 += h0 * a0 + h1 * a1 + h2 * a2 + h3 * a3;
            }
            for (; j < ne; ++j) {
                int c0 = s_co[w][j];
                float a0 = s_al[w][j];
                uint32_t b0 = hb[(size_t)c0 * 64 + lane];
                f32x2 h0; h0.x = __uint_as_float(b0 << 16); h0.y = __uint_as_float(b0 & 0xffff0000u);
                acc2 += h0 * a0;
            }
        }
    } else {
        float m = -3e38f, dsum = 0.f, sumec = 0.f;
        for (int base = 0; base < deg; base += 64) {
            int jj = base + lane;
            bool v = jj < deg;
            uint4 r = v ? rec[beg + jj] : make_uint4(0u, 0u, 0u, 0u);
            uint32_t ecu = lsel == 0 ? r.y : (lsel == 1 ? r.z : r.w);
            float ec = __uint_as_float(ecu);
            float a = v ? (hs[(int)r.x] + hdi + ec) : -3e38f;
            a = a > 0.f ? a : 0.2f * a;
            sumec += wred_sum(v ? ec : 0.f);
            float cm = wred_max(a);
            float nm = fmaxf(m, cm);
            dsum = dsum * __expf(m - nm) + wred_sum(__expf(a - nm));
            m = nm;
        }
        float ecs = sumec / (float)deg;
        float as_ = hsi + hdi + ecs;
        as_ = as_ > 0.f ? as_ : 0.2f * as_;
        float nm = fmaxf(m, as_);
        dsum = dsum * __expf(m - nm) + __expf(as_ - nm);
        m = nm;
        float inv = 1.f / dsum;
        for (int base = 0; base < deg; base += 64) {
            int jj = base + lane;
            bool v = jj < deg;
            uint4 r = v ? rec[beg + jj] : make_uint4(0u, 0u, 0u, 0u);
            int col = (int)r.x;
            uint32_t ecu = lsel == 0 ? r.y : (lsel == 1 ? r.z : r.w);
            float ec = __uint_as_float(ecu);
            float a = v ? (hs[col] + hdi + ec) : -3e38f;
            a = a > 0.f ? a : 0.2f * a;
            __asm__ volatile("s_waitcnt lgkmcnt(0)" ::: "memory");
            s_al[w][lane] = __expf(a - m) * inv;
            s_co[w][lane] = col;
            __asm__ volatile("s_waitcnt lgkmcnt(0)" ::: "memory");
            int cnt2 = min(64, deg - base);
            for (int k = 0; k < cnt2; ++k) {
                int c = s_co[w][k];
                float al = s_al[w][k];
                uint32_t b = hb[(size_t)c * 64 + lane];
                f32x2 h0; h0.x = __uint_as_float(b << 16); h0.y = __uint_as_float(b & 0xffff0000u);
                acc2 += h0 * al;
            }
        }
        float alS = __expf(as_ - m) * inv;
        uint32_t b = hb[(size_t)wid * 64 + lane];
        f32x2 hS; hS.x = __uint_as_float(b << 16); hS.y = __uint_as_float(b & 0xffff0000u);
        acc2 += hS * alS;
    }

    float2 bi = *(const float2*)&bias[lane * 2];
    float o0 = acc2.x + bi.x, o1 = acc2.y + bi.y;
    float mean = wred_sum(o0 + o1) * (1.f / 128.f);
    float d0 = o0 - mean, d1 = o1 - mean;
    float var = wred_sum(d0 * d0 + d1 * d1) * (1.f / 128.f);
    float rstd = rsqrtf(var + 1e-5f);
    float2 g = *(const float2*)&gamma[lane * 2];
    float2 be = *(const float2*)&beta[lane * 2];
    float2 o;
    o.x = d0 * rstd * g.x + be.x;
    o.y = d1 * rstd * g.y + be.y;
    if (outf) {
        *(float2*)&outf[(size_t)wid * D + lane * 2] = o;
    } else {
        outb[(size_t)wid * 64 + lane] = f2bf_rne(o.x) | (f2bf_rne(o.y) << 16);
    }
}

// ---------------- launch ----------------

extern "C" void kernel_launch(void* const* d_in, const int* in_sizes, int n_in,
                              void* d_out, int out_size, void* d_ws, size_t ws_size,
                              hipStream_t stream) {
    const float* x = (const float*)d_in[0];
    const int* ei = (const int*)d_in[1];
    const float* ea = (const float*)d_in[2];
    const float* W = (const float*)d_in[3];
    const float* att_src = (const float*)d_in[4];
    const float* att_dst = (const float*)d_in[5];
    const float* We = (const float*)d_in[6];
    const float* att_edge = (const float*)d_in[7];
    const float* bias = (const float*)d_in[8];
    const float* gamma = (const float*)d_in[9];
    const float* beta = (const float*)d_in[10];

    int N = in_sizes[0] / D;
    int E = in_sizes[1] / 2;
    const int* srcA = ei;
    const int* dstA = ei + E;

    float* p = (float*)d_ws;
    float* hsb = p;   p += N;
    float* hdb = p;   p += N;
    float* vbuf = p;  p += LNUM * D + 128;
    uint16_t* hbf = (uint16_t*)p;
    uint16_t* hnb = hbf + (size_t)N * D;
    uint16_t* Wt = hnb + (size_t)N * D;
    uint4* rec = (uint4*)(Wt + (size_t)LNUM * D * D);
    int* ip = (int*)(rec + E);
    int* rowptr = ip; ip += N + 1;
    int* cnt = ip;    ip += N;

    hipMemsetAsync(cnt, 0, sizeof(int) * N, stream);
    pre_k<<<1024, 256, 0, stream>>>(W, We, att_edge, dstA, Wt, vbuf, cnt, E);
    scan_k<<<1, 1024, 0, stream>>>(cnt, rowptr, N);

    int NB_G = (N + 63) / 64;
    int NB_F = (E + 31) / 32;
    fg_k<<<NB_G + NB_F, 256, 0, stream>>>(x, Wt, att_src, att_dst, hbf, hsb, hdb, N,
                                          ea, vbuf, srcA, dstA, rowptr, cnt, (uint32_t*)rec, E, NB_G);
    node_k<<<(N + 3) / 4, 256, 0, stream>>>((const uint32_t*)hbf, hsb, hdb, rec, rowptr,
                                            bias, gamma, beta, (uint32_t*)hnb, nullptr, N, 0);

    const uint16_t* hin = hnb;
    for (int l = 1; l < LNUM; ++l) {
        gemm_mfma_k<<<(N + 63) / 64, 256, 0, stream>>>(hin, Wt + (size_t)l * D * D,
                                                       att_src + (size_t)l * D, att_dst + (size_t)l * D,
                                                       hbf, hsb, hdb, N);
        bool last = (l == LNUM - 1);
        node_k<<<(N + 3) / 4, 256, 0, stream>>>((const uint32_t*)hbf, hsb, hdb, rec, rowptr,
                                                bias + (size_t)l * D, gamma + (size_t)l * D,
                                                beta + (size_t)l * D,
                                                last ? nullptr : (uint32_t*)hnb,
                                                last ? (float*)d_out : nullptr, N, l);
        hin = hnb;
    }
}